// Round 11
// baseline (297.562 us; speedup 1.0000x reference)
//
#include <hip/hip_runtime.h>

#define N_NODES 50000
#define N_EDGES 800000
#define HID 128
#define EPS 1e-5f
#define NBKT 782            // ceil(50000/64) buckets of 64 dst nodes
#define ESLICE 3125         // edges per scatter/hist block (256 blocks)
#define NSLICE 256

typedef __attribute__((ext_vector_type(8))) short s16x8;   // 8 bf16 (4 VGPRs)
typedef __attribute__((ext_vector_type(4))) float f32x4;   // MFMA acc
typedef __attribute__((ext_vector_type(4))) int i32x4;

__device__ __forceinline__ unsigned short f2bf(float f) {  // RNE f32->bf16
  unsigned int u = __float_as_uint(f);
  u += 0x7fffu + ((u >> 16) & 1u);
  return (unsigned short)(u >> 16);
}
__device__ __forceinline__ unsigned int pack2(float a, float b) {
  return (unsigned int)f2bf(a) | ((unsigned int)f2bf(b) << 16);
}
__device__ __forceinline__ float bflo(unsigned int u) { return __uint_as_float(u << 16); }
__device__ __forceinline__ float bfhi(unsigned int u) { return __uint_as_float(u & 0xffff0000u); }
__device__ __forceinline__ float bf2f(unsigned short u) { return __uint_as_float((unsigned int)u << 16); }

// ================= weight prep (blocks 0..448)  ||  bucket hist (blocks 449..704) =================
__global__ __launch_bounds__(256) void prep_hist_kernel(
    const float* __restrict__ W_enc, const float* __restrict__ W_out,
    const float* __restrict__ Wm1, const float* __restrict__ Wu,
    const float* __restrict__ Wm2, const float* __restrict__ bm2,
    unsigned int* __restrict__ Wenc_b, unsigned int* __restrict__ Wout_b,
    unsigned int* __restrict__ Wpq_b, unsigned short* __restrict__ Wcat_b,
    float* __restrict__ bfold, const int* __restrict__ ei, int* __restrict__ shist) {
  __shared__ int lhist[NBKT];
  const int b = blockIdx.x, t = threadIdx.x;
  if (b >= 449) {  // ---- bucket histogram (one slice per block) ----
    const int sl = b - 449;
    const int e0 = sl * ESLICE;
    for (int i = t; i < NBKT; i += 256) lhist[i] = 0;
    __syncthreads();
    for (int e = e0 + t; e < e0 + ESLICE; e += 256)
      atomicAdd(&lhist[ei[N_EDGES + e] >> 6], 1);
    __syncthreads();
    for (int i = t; i < NBKT; i += 256) shist[sl * NBKT + i] = lhist[i];
    return;
  }
  if (b < 32) {            // W_enc: 8192 uints
    int i = b * 256 + t;
    Wenc_b[i] = pack2(W_enc[2 * i], W_enc[2 * i + 1]);
  } else if (b < 64) {     // W_out
    int i = (b - 32) * 256 + t;
    Wout_b[i] = pack2(W_out[2 * i], W_out[2 * i + 1]);
  } else if (b < 192) {    // repack Wm1 -> Wpq [l][256 rows][128 k]
    int i = (b - 64) * 256 + t;  // 32768
    int k2 = i & 63;
    int c = (i >> 6) & 255;
    int l = i >> 14;
    const float* srow = Wm1 + ((size_t)l * 128 + (c & 127)) * 256 + ((c >> 7) << 7);
    Wpq_b[i] = pack2(srow[2 * k2], srow[2 * k2 + 1]);
  } else if (b < 448) {    // Wcat: [l][128 rows][256 k], hi-k = Wu_b @ Wm2 fold
    int i = (b - 192) * 256 + t;  // 65536
    int k = i & 255, c = (i >> 8) & 127, l = i >> 15;
    const float* wrow = Wu + ((size_t)l * 128 + c) * 256;
    float v;
    if (k < 128) {
      v = wrow[k];
    } else {
      const float* wb = wrow + 128;
      const float* m2 = Wm2 + (size_t)l * 128 * 128 + (k - 128);
      float s = 0.f;
      for (int j = 0; j < 128; ++j) s += wb[j] * m2[(size_t)j * 128];
      v = s;
    }
    Wcat_b[i] = f2bf(v);
  } else {                 // bfold[l][c] = Wu_b[l][c][:] . bm2[l]
    int l = t >> 7, c = t & 127;
    const float* wb = Wu + ((size_t)l * 128 + c) * 256 + 128;
    const float* bv = bm2 + l * 128;
    float s = 0.f;
    for (int j = 0; j < 128; ++j) s += wb[j] * bv[j];
    bfold[t] = s;
  }
}

// ================= bucket scan (with fused column-sum of slice hists) =================
__global__ __launch_bounds__(1024) void bscan_kernel(const int* __restrict__ shist,
                                                     int* __restrict__ boff,
                                                     int* __restrict__ bcursor) {
  __shared__ int wtot[16];
  const int t = threadIdx.x, lane = t & 63, w = t >> 6;
  int v = 0;
  if (t < NBKT)
    for (int j = 0; j < NSLICE; ++j) v += shist[j * NBKT + t];  // coalesced across t
  int s = v;
#pragma unroll
  for (int off = 1; off < 64; off <<= 1) {
    int tt = __shfl_up(s, off);
    if (lane >= off) s += tt;
  }
  if (lane == 63) wtot[w] = s;
  __syncthreads();
  int woff = 0;
#pragma unroll
  for (int j = 0; j < 16; ++j) { int tv = wtot[j]; if (j < w) woff += tv; }
  int excl = woff + (s - v);
  if (t < NBKT) { boff[t] = excl; bcursor[t] = excl; }
  if (t == NBKT) boff[NBKT] = excl;  // v=0 here -> excl == total
}

// ================= device-fn bodies for merged kernels =================
struct BscatSmem {
  int lhist[784], lstart[784], lcur[784], gbase[784];
  unsigned int staged[ESLICE];
  int wtot[4];
};
struct Sort64Smem { int hist[64]; int lcur[64]; };

// bucket scatter: 2-pass LDS counting sort per 3125-edge slice.
__device__ __forceinline__ void bscatter_dev(BscatSmem& sm, const int* ei, int* bcursor,
                                             unsigned int* ebuf, int bx) {
  const int t = threadIdx.x, lane = t & 63, w = t >> 6;
  const int e0 = bx * ESLICE;

  for (int i = t; i < 784; i += 256) sm.lhist[i] = 0;
  __syncthreads();
  for (int e = e0 + t; e < e0 + ESLICE; e += 256)
    atomicAdd(&sm.lhist[ei[N_EDGES + e] >> 6], 1);
  __syncthreads();

  int tsum = 0;
  if (t < 196)
    tsum = sm.lhist[4 * t] + sm.lhist[4 * t + 1] + sm.lhist[4 * t + 2] + sm.lhist[4 * t + 3];
  int inc = tsum;
#pragma unroll
  for (int off = 1; off < 64; off <<= 1) {
    int tt = __shfl_up(inc, off);
    if (lane >= off) inc += tt;
  }
  if (lane == 63) sm.wtot[w] = inc;
  __syncthreads();
  int woff = 0;
#pragma unroll
  for (int j = 0; j < 4; ++j) { int tv = sm.wtot[j]; if (j < w) woff += tv; }
  if (t < 196) {
    int run = woff + inc - tsum;
#pragma unroll
    for (int j = 0; j < 4; ++j) {
      sm.lstart[4 * t + j] = run;
      sm.lcur[4 * t + j] = run;
      run += sm.lhist[4 * t + j];
    }
  }
  for (int bk = t; bk < NBKT; bk += 256)
    sm.gbase[bk] = sm.lhist[bk] ? atomicAdd(&bcursor[bk], sm.lhist[bk]) : 0;
  __syncthreads();

  for (int e = e0 + t; e < e0 + ESLICE; e += 256) {
    int s = ei[e], d = ei[N_EDGES + e];
    int pos = atomicAdd(&sm.lcur[d >> 6], 1);
    sm.staged[pos] = (unsigned int)s | ((unsigned int)(d & 63) << 16) |
                     ((unsigned int)(d >> 6) << 22);
  }
  __syncthreads();

  for (int i = t; i < ESLICE; i += 256) {
    unsigned int pk = sm.staged[i];
    int bk = pk >> 22;
    ebuf[sm.gbase[bk] + (i - sm.lstart[bk])] = pk;
  }
}

// sort64: bucket -> exact per-node CSR; esrc stored as u16 (src < 65536).
__device__ __forceinline__ void sort64_dev(Sort64Smem& sm, const unsigned int* ebuf,
                                           const int* boff, unsigned short* esrc,
                                           int* noff, int* counts, int b) {
  const int t = threadIdx.x;
  const int e0 = boff[b], e1 = boff[b + 1];
  if (t < 64) sm.hist[t] = 0;
  __syncthreads();
  for (int e = e0 + t; e < e1; e += 256)
    atomicAdd(&sm.hist[(ebuf[e] >> 16) & 63], 1);
  __syncthreads();
  if (t < 64) {
    int v = sm.hist[t];
    int s = v;
#pragma unroll
    for (int off = 1; off < 64; off <<= 1) {
      int tt = __shfl_up(s, off);
      if (t >= off) s += tt;
    }
    sm.lcur[t] = s - v;
    int node = b * 64 + t;
    if (node < N_NODES) {
      noff[node] = e0 + s - v;
      counts[node] = v;
    }
  }
  __syncthreads();
  for (int e = e0 + t; e < e1; e += 256) {
    unsigned int pk = ebuf[e];
    int pos = atomicAdd(&sm.lcur[(pk >> 16) & 63], 1);
    esrc[e0 + pos] = (unsigned short)(pk & 0xffffu);
  }
  if (b == NBKT - 1 && t == 0) noff[N_NODES] = e1;
}

// ================= persistent-B MFMA GEMM body =================
// CMOUT: store bf16 out channel-major [group=col/16][node][16].
// A1CM : DUAL second operand (rb) is channel-major [group=k/16][node][16].
template <int KS, bool AF32, bool DUAL, int MODE, bool CMOUT = false, bool A1CM = false>
__device__ __forceinline__ void gemm3_dev(
    short* Bs, int bx, int gx, int by,
    const void* A0v, const unsigned short* A1,
    const unsigned short* W, const float* bias,
    const int* deg, const float* bias2,
    const float* gamma, const float* beta,
    const unsigned short* hres, float* outF,
    unsigned short* outB, int outw) {
  constexpr int KW = KS * 32;
  constexpr int NFRAG = KS * 8;
  const int lane = threadIdx.x & 63;
  const int w = threadIdx.x >> 6;
  const int cl = lane & 15;
  const int kb = (lane >> 4) * 8;
  const int co = by * 128;
  W += (size_t)by * 128 * KW;

  for (int f = w; f < NFRAG; f += 4) {
    int nt = f & 7, ks = f >> 3;
    s16x8 bv = *(const s16x8*)(W + (size_t)(nt * 16 + cl) * KW + ks * 32 + kb);
    *(s16x8*)(Bs + f * 512 + lane * 8) = bv;
  }
  __syncthreads();

  s16x8 breg[KS][8];
#pragma unroll
  for (int ks = 0; ks < KS; ++ks)
#pragma unroll
    for (int nt = 0; nt < 8; ++nt)
      breg[ks][nt] = *(const s16x8*)(Bs + (ks * 8 + nt) * 512 + lane * 8);

  float bs[8], b2[8], gs[8], bes[8];
#pragma unroll
  for (int nt = 0; nt < 8; ++nt) {
    int col = nt * 16 + cl;
    bs[nt] = bias ? bias[col] : 0.f;
    if constexpr (MODE == 2) {
      b2[nt] = bias2[col];
      gs[nt] = gamma[col];
      bes[nt] = beta[col];
    }
  }

  const int step = gx * 4;
  for (int rt = bx * 4 + w; rt < 3125; rt += step) {  // 3125*16 == 50000
    const int arow = rt * 16 + cl;
    f32x4 acc[8];
#pragma unroll
    for (int i = 0; i < 8; ++i) acc[i] = (f32x4){0.f, 0.f, 0.f, 0.f};
#pragma unroll
    for (int ks = 0; ks < KS; ++ks) {
      s16x8 a;
      if constexpr (AF32) {
        const float* ap = (const float*)A0v + (size_t)arow * HID + ks * 32 + kb;
        float4 lo = *(const float4*)ap;
        float4 hi = *(const float4*)(ap + 4);
        i32x4 ai = {(int)pack2(lo.x, lo.y), (int)pack2(lo.z, lo.w),
                    (int)pack2(hi.x, hi.y), (int)pack2(hi.z, hi.w)};
        a = __builtin_bit_cast(s16x8, ai);
      } else if constexpr (DUAL) {
        if (ks < KS / 2) {
          a = *(const s16x8*)((const unsigned short*)A0v + (size_t)arow * HID + ks * 32 + kb);
        } else {
          int kk = (ks - KS / 2) * 32 + kb;
          if constexpr (A1CM)
            a = *(const s16x8*)(A1 + ((size_t)(kk >> 4) * N_NODES + arow) * 16 + (kk & 15));
          else
            a = *(const s16x8*)(A1 + (size_t)arow * HID + kk);
        }
      } else {
        a = *(const s16x8*)((const unsigned short*)A0v + (size_t)arow * HID + ks * 32 + kb);
      }
#pragma unroll
      for (int nt = 0; nt < 8; ++nt)
        acc[nt] = __builtin_amdgcn_mfma_f32_16x16x32_bf16(a, breg[ks][nt], acc[nt], 0, 0, 0);
    }

    const int rbase = rt * 16 + (lane >> 4) * 4;
    if constexpr (MODE == 2) {
#pragma unroll
      for (int reg = 0; reg < 4; ++reg) {
        int row = rbase + reg;
        float dv = (float)deg[row];
        float v[8];
        float s = 0.f, s2 = 0.f;
#pragma unroll
        for (int nt = 0; nt < 8; ++nt) {
          float hv = bf2f(hres[(size_t)row * HID + nt * 16 + cl]);
          v[nt] = acc[nt][reg] + bs[nt] + dv * b2[nt] + hv;
          s += v[nt];
          s2 += v[nt] * v[nt];
        }
#pragma unroll
        for (int m = 1; m < 16; m <<= 1) {
          s += __shfl_xor(s, m);
          s2 += __shfl_xor(s2, m);
        }
        float mu = s * (1.f / 128.f);
        float var = s2 * (1.f / 128.f) - mu * mu;
        float inv = rsqrtf(var + EPS);
#pragma unroll
        for (int nt = 0; nt < 8; ++nt) {
          float o = (v[nt] - mu) * inv * gs[nt] + bes[nt];
          outB[(size_t)row * HID + nt * 16 + cl] = f2bf(o);
        }
      }
    } else {
#pragma unroll
      for (int reg = 0; reg < 4; ++reg) {
        int row = rbase + reg;
#pragma unroll
        for (int nt = 0; nt < 8; ++nt) {
          float vv = acc[nt][reg] + bs[nt];
          if constexpr (MODE == 0) outF[(size_t)row * outw + co + nt * 16 + cl] = vv;
          else if constexpr (CMOUT)
            outB[((size_t)(by * 8 + nt) * N_NODES + row) * 16 + cl] = f2bf(vv);
          else outB[(size_t)row * outw + co + nt * 16 + cl] = f2bf(vv);
        }
      }
    }
  }
}

// standalone GEMM kernel
template <int KS, bool AF32, bool DUAL, int MODE, bool CMOUT = false, bool A1CM = false>
__global__ __launch_bounds__(256, DUAL ? 1 : 2) void gemm3(
    const void* __restrict__ A0v, const unsigned short* __restrict__ A1,
    const unsigned short* __restrict__ W, const float* __restrict__ bias,
    const int* __restrict__ deg, const float* __restrict__ bias2,
    const float* __restrict__ gamma, const float* __restrict__ beta,
    const unsigned short* __restrict__ hres, float* __restrict__ outF,
    unsigned short* __restrict__ outB, int outw) {
  __shared__ short Bs[KS * 8 * 512];
  gemm3_dev<KS, AF32, DUAL, MODE, CMOUT, A1CM>(Bs, blockIdx.x, gridDim.x, blockIdx.y, A0v,
                                               A1, W, bias, deg, bias2, gamma, beta, hres,
                                               outF, outB, outw);
}

// ================= merged kernels: CSR stages hidden under GEMM =================
union MergedSmem1 { BscatSmem b; short Bs[32 * 512]; };
__global__ __launch_bounds__(256, 2) void k_bscat_enc(
    const int* __restrict__ ei, int* __restrict__ bcursor, unsigned int* __restrict__ ebuf,
    const float* __restrict__ x, const unsigned short* __restrict__ Wenc,
    const float* __restrict__ b_enc, unsigned short* __restrict__ hb) {
  __shared__ MergedSmem1 sm;
  if (blockIdx.x < NSLICE) {
    bscatter_dev(sm.b, ei, bcursor, ebuf, blockIdx.x);
  } else {
    gemm3_dev<4, true, false, 1>(sm.Bs, blockIdx.x - NSLICE, 512, 0, x, nullptr, Wenc, b_enc,
                                 nullptr, nullptr, nullptr, nullptr, nullptr, nullptr, hb, HID);
  }
}

union MergedSmem2 { Sort64Smem s; short Bs[32 * 512]; };
__global__ __launch_bounds__(256, 2) void k_sort_pq(
    const unsigned int* __restrict__ ebuf, const int* __restrict__ boff,
    unsigned short* __restrict__ esrc, int* __restrict__ noff, int* __restrict__ counts,
    const unsigned short* __restrict__ hb, const unsigned short* __restrict__ Wpq,
    unsigned short* __restrict__ pq) {
  __shared__ MergedSmem2 sm;
  if (blockIdx.x < NBKT) {
    sort64_dev(sm.s, ebuf, boff, esrc, noff, counts, blockIdx.x);
  } else {
    int bb = blockIdx.x - NBKT;
    gemm3_dev<4, false, false, 1, true>(sm.Bs, bb & 511, 512, bb >> 9, hb, nullptr, Wpq,
                                        nullptr, nullptr, nullptr, nullptr, nullptr, nullptr,
                                        nullptr, pq, 256);
  }
}

// ================= aggregation: channel-partitioned, XCD-local slices =================
// cg = blockIdx&7 -> one 16-channel group; pq/rb channel-major [group][node][16].
// Wave = 8 edges x 8 lanes x 1 uint; reduce over edge slots with shfl_xor 8/16/32.
__global__ __launch_bounds__(256) void aggregate6_kernel(
    const unsigned int* __restrict__ pqcm,   // [16][N][8] uints: groups 0-7 = p, 8-15 = q
    const float* __restrict__ bm1,
    const int* __restrict__ noff, const unsigned short* __restrict__ esrc,
    unsigned int* __restrict__ rbcm) {       // [8][N][8] uints
  const int cg = blockIdx.x & 7;
  const int chunk = blockIdx.x >> 3;
  const int lane = threadIdx.x & 63;
  const int w = threadIdx.x >> 6;
  const int es = lane >> 3;   // edge slot 0..7
  const int ch = lane & 7;    // uint (channel pair) within group
  const unsigned int* pbase = pqcm + (size_t)cg * N_NODES * 8;
  const unsigned int* qbase = pqcm + (size_t)(8 + cg) * N_NODES * 8;
  unsigned int* rbase = rbcm + (size_t)cg * N_NODES * 8;
  float2 bmv = *(const float2*)(bm1 + 2 * (cg * 8 + ch));
  const int nbase = chunk * 16 + w * 4;
#pragma unroll
  for (int nn = 0; nn < 4; ++nn) {
    const int node = nbase + nn;
    unsigned int qv = qbase[(size_t)node * 8 + ch];
    float q0 = bflo(qv) + bmv.x, q1 = bfhi(qv) + bmv.y;
    float a0 = 0.f, a1 = 0.f;
    const int i0 = noff[node], i1 = noff[node + 1];
    int idx = i0 + es;
    const int nfull = (i1 - i0) >> 3;
    for (int j = 0; j < nfull; ++j, idx += 8) {
      int src = esrc[idx];
      unsigned int u = pbase[(size_t)src * 8 + ch];
      a0 += fmaxf(bflo(u) + q0, 0.f);
      a1 += fmaxf(bfhi(u) + q1, 0.f);
    }
    if (idx < i1) {  // tail <8 edges, exec-masked
      int src = esrc[idx];
      unsigned int u = pbase[(size_t)src * 8 + ch];
      a0 += fmaxf(bflo(u) + q0, 0.f);
      a1 += fmaxf(bfhi(u) + q1, 0.f);
    }
    a0 += __shfl_xor(a0, 8);  a1 += __shfl_xor(a1, 8);
    a0 += __shfl_xor(a0, 16); a1 += __shfl_xor(a1, 16);
    a0 += __shfl_xor(a0, 32); a1 += __shfl_xor(a1, 32);
    if (es == 0) rbase[(size_t)node * 8 + ch] = pack2(a0, a1);
  }
}

extern "C" void kernel_launch(void* const* d_in, const int* in_sizes, int n_in,
                              void* d_out, int out_size, void* d_ws, size_t ws_size,
                              hipStream_t stream) {
  const float* x     = (const float*)d_in[0];
  const int*   ei    = (const int*)d_in[1];
  const float* W_enc = (const float*)d_in[2];
  const float* b_enc = (const float*)d_in[3];
  const float* Wm1   = (const float*)d_in[4];
  const float* bm1   = (const float*)d_in[5];
  const float* Wm2   = (const float*)d_in[6];
  const float* bm2   = (const float*)d_in[7];
  const float* Wu    = (const float*)d_in[8];
  const float* bu    = (const float*)d_in[9];
  const float* gamma = (const float*)d_in[10];
  const float* beta  = (const float*)d_in[11];
  const float* W_out = (const float*)d_in[12];
  const float* b_out = (const float*)d_in[13];
  float* out = (float*)d_out;

  char* ws = (char*)d_ws;
  const size_t NBH = (size_t)N_NODES * HID * 2;  // 12.8 MB

  unsigned short* hb = (unsigned short*)(ws);            // [N][128] bf16 row-major
  unsigned short* pq = (unsigned short*)(ws + NBH);      // [16][N][16] bf16 channel-major
  unsigned short* rb = (unsigned short*)(ws + 3 * NBH);  // [8][N][16] bf16 channel-major
  char* wp = ws + 4 * NBH;
  unsigned short* Wenc_b = (unsigned short*)wp;          // 16384
  unsigned short* Wout_b = Wenc_b + 16384;               // 16384
  unsigned short* Wpq_b  = Wout_b + 16384;               // 2*32768
  unsigned short* Wcat_b = Wpq_b + 65536;                // 2*32768
  float*          bfold  = (float*)(Wcat_b + 65536);     // 256
  int* counts  = (int*)(bfold + 256);                    // [N] deg
  int* noff    = counts + N_NODES;                       // [N+1] exact CSR offsets
  int* boff    = noff + N_NODES + 1;                     // NBKT+1
  int* bcursor = boff + NBKT + 1;                        // NBKT
  unsigned short* esrc = (unsigned short*)(bcursor + NBKT);  // [E] u16 src by exact dst
  unsigned int* ebuf = (unsigned int*)(esrc + N_EDGES);      // [E] bucket-grouped
  int* shist = (int*)(ebuf + N_EDGES);                       // [NSLICE][NBKT]

  // 1. weight prep || per-slice bucket histograms
  prep_hist_kernel<<<449 + NSLICE, 256, 0, stream>>>(
      W_enc, W_out, Wm1, Wu, Wm2, bm2, (unsigned int*)Wenc_b, (unsigned int*)Wout_b,
      (unsigned int*)Wpq_b, Wcat_b, bfold, ei, shist);
  // 2. fused column-sum + exclusive scan
  bscan_kernel<<<1, 1024, 0, stream>>>(shist, boff, bcursor);
  // 3. bucket scatter || enc GEMM (h = x @ W_enc.T + b_enc -> bf16 hb)
  k_bscat_enc<<<NSLICE + 512, 256, 0, stream>>>(ei, bcursor, ebuf, x, Wenc_b, b_enc, hb);
  // 4. sort64 (exact CSR) || pq GEMM layer 0 (channel-major out)
  k_sort_pq<<<NBKT + 1024, 256, 0, stream>>>(ebuf, boff, esrc, noff, counts, hb, Wpq_b, pq);

  for (int l = 0; l < 2; ++l) {
    const unsigned short* Wcatl = Wcat_b + l * 32768;
    const float* bm1l = bm1 + l * HID;
    const float* bul  = bu + l * HID;
    const float* bfl  = bfold + l * HID;
    const float* gl   = gamma + l * HID;
    const float* bl   = beta + l * HID;

    // r = segsum(relu(p[src]+q[dst]+bm1)), channel-partitioned (cg = bid&7)
    aggregate6_kernel<<<3125 * 8, 256, 0, stream>>>((const unsigned int*)pq, bm1l, noff,
                                                    esrc, (unsigned int*)rb);
    // h = LN(h + h@Wua.T + r@Wfold.T + deg*bfold + bu)*gamma+beta (in-place; rb channel-major)
    gemm3<8, false, true, 2, false, true><<<256, 256, 0, stream>>>(
        hb, rb, Wcatl, bul, counts, bfl, gl, bl, hb, nullptr, hb, HID);
    // pq for layer 1 (channel-major out)
    if (l == 0)
      gemm3<4, false, false, 1, true><<<dim3(512, 2), 256, 0, stream>>>(
          hb, nullptr, Wpq_b + 32768, nullptr, nullptr, nullptr, nullptr, nullptr, nullptr,
          nullptr, pq, 256);
  }

  // out = h @ W_out.T + b_out (f32)
  gemm3<4, false, false, 0><<<512, 256, 0, stream>>>(
      hb, nullptr, Wout_b, b_out, nullptr, nullptr, nullptr, nullptr, nullptr,
      out, nullptr, HID);
}

// Round 12
// 280.831 us; speedup vs baseline: 1.0596x; 1.0596x over previous
//
#include <hip/hip_runtime.h>

#define N_NODES 50000
#define N_EDGES 800000
#define HID 128
#define EPS 1e-5f
#define NBKT 782            // ceil(50000/64) buckets of 64 dst nodes
#define ESLICE 3125         // edges per scatter/hist block (256 blocks)
#define NSLICE 256

typedef __attribute__((ext_vector_type(8))) short s16x8;   // 8 bf16 (4 VGPRs)
typedef __attribute__((ext_vector_type(4))) float f32x4;   // MFMA acc
typedef __attribute__((ext_vector_type(4))) int i32x4;

__device__ __forceinline__ unsigned short f2bf(float f) {  // RNE f32->bf16
  unsigned int u = __float_as_uint(f);
  u += 0x7fffu + ((u >> 16) & 1u);
  return (unsigned short)(u >> 16);
}
__device__ __forceinline__ unsigned int pack2(float a, float b) {
  return (unsigned int)f2bf(a) | ((unsigned int)f2bf(b) << 16);
}
__device__ __forceinline__ float bflo(unsigned int u) { return __uint_as_float(u << 16); }
__device__ __forceinline__ float bfhi(unsigned int u) { return __uint_as_float(u & 0xffff0000u); }
__device__ __forceinline__ float bf2f(unsigned short u) { return __uint_as_float((unsigned int)u << 16); }

// ================= weight prep (blocks 0..448)  ||  bucket hist (blocks 449..704) =================
__global__ __launch_bounds__(256) void prep_hist_kernel(
    const float* __restrict__ W_enc, const float* __restrict__ W_out,
    const float* __restrict__ Wm1, const float* __restrict__ Wu,
    const float* __restrict__ Wm2, const float* __restrict__ bm2,
    unsigned int* __restrict__ Wenc_b, unsigned int* __restrict__ Wout_b,
    unsigned int* __restrict__ Wpq_b, unsigned short* __restrict__ Wcat_b,
    float* __restrict__ bfold, const int* __restrict__ ei, int* __restrict__ shist) {
  __shared__ int lhist[NBKT];
  const int b = blockIdx.x, t = threadIdx.x;
  if (b >= 449) {  // ---- bucket histogram (one slice per block) ----
    const int sl = b - 449;
    const int e0 = sl * ESLICE;
    for (int i = t; i < NBKT; i += 256) lhist[i] = 0;
    __syncthreads();
    for (int e = e0 + t; e < e0 + ESLICE; e += 256)
      atomicAdd(&lhist[ei[N_EDGES + e] >> 6], 1);
    __syncthreads();
    for (int i = t; i < NBKT; i += 256) shist[sl * NBKT + i] = lhist[i];
    return;
  }
  if (b < 32) {            // W_enc: 8192 uints
    int i = b * 256 + t;
    Wenc_b[i] = pack2(W_enc[2 * i], W_enc[2 * i + 1]);
  } else if (b < 64) {     // W_out
    int i = (b - 32) * 256 + t;
    Wout_b[i] = pack2(W_out[2 * i], W_out[2 * i + 1]);
  } else if (b < 192) {    // repack Wm1 -> Wpq [l][256 rows][128 k]
    int i = (b - 64) * 256 + t;  // 32768
    int k2 = i & 63;
    int c = (i >> 6) & 255;
    int l = i >> 14;
    const float* srow = Wm1 + ((size_t)l * 128 + (c & 127)) * 256 + ((c >> 7) << 7);
    Wpq_b[i] = pack2(srow[2 * k2], srow[2 * k2 + 1]);
  } else if (b < 448) {    // Wcat: [l][128 rows][256 k], hi-k = Wu_b @ Wm2 fold
    int i = (b - 192) * 256 + t;  // 65536
    int k = i & 255, c = (i >> 8) & 127, l = i >> 15;
    const float* wrow = Wu + ((size_t)l * 128 + c) * 256;
    float v;
    if (k < 128) {
      v = wrow[k];
    } else {
      const float* wb = wrow + 128;
      const float* m2 = Wm2 + (size_t)l * 128 * 128 + (k - 128);
      float s = 0.f;
      for (int j = 0; j < 128; ++j) s += wb[j] * m2[(size_t)j * 128];
      v = s;
    }
    Wcat_b[i] = f2bf(v);
  } else {                 // bfold[l][c] = Wu_b[l][c][:] . bm2[l]
    int l = t >> 7, c = t & 127;
    const float* wb = Wu + ((size_t)l * 128 + c) * 256 + 128;
    const float* bv = bm2 + l * 128;
    float s = 0.f;
    for (int j = 0; j < 128; ++j) s += wb[j] * bv[j];
    bfold[t] = s;
  }
}

// ================= bucket scan (with fused column-sum of slice hists) =================
__global__ __launch_bounds__(1024) void bscan_kernel(const int* __restrict__ shist,
                                                     int* __restrict__ boff,
                                                     int* __restrict__ bcursor) {
  __shared__ int wtot[16];
  const int t = threadIdx.x, lane = t & 63, w = t >> 6;
  int v = 0;
  if (t < NBKT)
    for (int j = 0; j < NSLICE; ++j) v += shist[j * NBKT + t];  // coalesced across t
  int s = v;
#pragma unroll
  for (int off = 1; off < 64; off <<= 1) {
    int tt = __shfl_up(s, off);
    if (lane >= off) s += tt;
  }
  if (lane == 63) wtot[w] = s;
  __syncthreads();
  int woff = 0;
#pragma unroll
  for (int j = 0; j < 16; ++j) { int tv = wtot[j]; if (j < w) woff += tv; }
  int excl = woff + (s - v);
  if (t < NBKT) { boff[t] = excl; bcursor[t] = excl; }
  if (t == NBKT) boff[NBKT] = excl;  // v=0 here -> excl == total
}

// ================= device-fn bodies for merged kernels =================
struct BscatSmem {
  int lhist[784], lstart[784], lcur[784], gbase[784];
  unsigned int staged[ESLICE];
  int wtot[4];
};
struct Sort64Smem { int hist[64]; int lcur[64]; };

// bucket scatter: 2-pass LDS counting sort per 3125-edge slice.
__device__ __forceinline__ void bscatter_dev(BscatSmem& sm, const int* ei, int* bcursor,
                                             unsigned int* ebuf, int bx) {
  const int t = threadIdx.x, lane = t & 63, w = t >> 6;
  const int e0 = bx * ESLICE;

  for (int i = t; i < 784; i += 256) sm.lhist[i] = 0;
  __syncthreads();
  for (int e = e0 + t; e < e0 + ESLICE; e += 256)
    atomicAdd(&sm.lhist[ei[N_EDGES + e] >> 6], 1);
  __syncthreads();

  int tsum = 0;
  if (t < 196)
    tsum = sm.lhist[4 * t] + sm.lhist[4 * t + 1] + sm.lhist[4 * t + 2] + sm.lhist[4 * t + 3];
  int inc = tsum;
#pragma unroll
  for (int off = 1; off < 64; off <<= 1) {
    int tt = __shfl_up(inc, off);
    if (lane >= off) inc += tt;
  }
  if (lane == 63) sm.wtot[w] = inc;
  __syncthreads();
  int woff = 0;
#pragma unroll
  for (int j = 0; j < 4; ++j) { int tv = sm.wtot[j]; if (j < w) woff += tv; }
  if (t < 196) {
    int run = woff + inc - tsum;
#pragma unroll
    for (int j = 0; j < 4; ++j) {
      sm.lstart[4 * t + j] = run;
      sm.lcur[4 * t + j] = run;
      run += sm.lhist[4 * t + j];
    }
  }
  for (int bk = t; bk < NBKT; bk += 256)
    sm.gbase[bk] = sm.lhist[bk] ? atomicAdd(&bcursor[bk], sm.lhist[bk]) : 0;
  __syncthreads();

  for (int e = e0 + t; e < e0 + ESLICE; e += 256) {
    int s = ei[e], d = ei[N_EDGES + e];
    int pos = atomicAdd(&sm.lcur[d >> 6], 1);
    sm.staged[pos] = (unsigned int)s | ((unsigned int)(d & 63) << 16) |
                     ((unsigned int)(d >> 6) << 22);
  }
  __syncthreads();

  for (int i = t; i < ESLICE; i += 256) {
    unsigned int pk = sm.staged[i];
    int bk = pk >> 22;
    ebuf[sm.gbase[bk] + (i - sm.lstart[bk])] = pk;
  }
}

// sort64: bucket -> exact per-node CSR; esrc stored as u16 (src < 65536).
__device__ __forceinline__ void sort64_dev(Sort64Smem& sm, const unsigned int* ebuf,
                                           const int* boff, unsigned short* esrc,
                                           int* noff, int* counts, int b) {
  const int t = threadIdx.x;
  const int e0 = boff[b], e1 = boff[b + 1];
  if (t < 64) sm.hist[t] = 0;
  __syncthreads();
  for (int e = e0 + t; e < e1; e += 256)
    atomicAdd(&sm.hist[(ebuf[e] >> 16) & 63], 1);
  __syncthreads();
  if (t < 64) {
    int v = sm.hist[t];
    int s = v;
#pragma unroll
    for (int off = 1; off < 64; off <<= 1) {
      int tt = __shfl_up(s, off);
      if (t >= off) s += tt;
    }
    sm.lcur[t] = s - v;
    int node = b * 64 + t;
    if (node < N_NODES) {
      noff[node] = e0 + s - v;
      counts[node] = v;
    }
  }
  __syncthreads();
  for (int e = e0 + t; e < e1; e += 256) {
    unsigned int pk = ebuf[e];
    int pos = atomicAdd(&sm.lcur[(pk >> 16) & 63], 1);
    esrc[e0 + pos] = (unsigned short)(pk & 0xffffu);
  }
  if (b == NBKT - 1 && t == 0) noff[N_NODES] = e1;
}

// ================= persistent-B MFMA GEMM body =================
// CMOUT: store bf16 out 32-ch-group-major: idx = ((part*4+cg)*N + row)*32 + ch,
//        part = col>>7, cg = (col&127)>>5, ch = col&31.
// A1CM : DUAL second operand (rb) is [4][N][32]: idx = ((kk>>5)*N + row)*32 + (kk&31).
template <int KS, bool AF32, bool DUAL, int MODE, bool CMOUT = false, bool A1CM = false>
__device__ __forceinline__ void gemm3_dev(
    short* Bs, int bx, int gx, int by,
    const void* A0v, const unsigned short* A1,
    const unsigned short* W, const float* bias,
    const int* deg, const float* bias2,
    const float* gamma, const float* beta,
    const unsigned short* hres, float* outF,
    unsigned short* outB, int outw) {
  constexpr int KW = KS * 32;
  constexpr int NFRAG = KS * 8;
  const int lane = threadIdx.x & 63;
  const int w = threadIdx.x >> 6;
  const int cl = lane & 15;
  const int kb = (lane >> 4) * 8;
  const int co = by * 128;
  W += (size_t)by * 128 * KW;

  for (int f = w; f < NFRAG; f += 4) {
    int nt = f & 7, ks = f >> 3;
    s16x8 bv = *(const s16x8*)(W + (size_t)(nt * 16 + cl) * KW + ks * 32 + kb);
    *(s16x8*)(Bs + f * 512 + lane * 8) = bv;
  }
  __syncthreads();

  s16x8 breg[KS][8];
#pragma unroll
  for (int ks = 0; ks < KS; ++ks)
#pragma unroll
    for (int nt = 0; nt < 8; ++nt)
      breg[ks][nt] = *(const s16x8*)(Bs + (ks * 8 + nt) * 512 + lane * 8);

  float bs[8], b2[8], gs[8], bes[8];
#pragma unroll
  for (int nt = 0; nt < 8; ++nt) {
    int col = nt * 16 + cl;
    bs[nt] = bias ? bias[col] : 0.f;
    if constexpr (MODE == 2) {
      b2[nt] = bias2[col];
      gs[nt] = gamma[col];
      bes[nt] = beta[col];
    }
  }

  const int step = gx * 4;
  for (int rt = bx * 4 + w; rt < 3125; rt += step) {  // 3125*16 == 50000
    const int arow = rt * 16 + cl;
    f32x4 acc[8];
#pragma unroll
    for (int i = 0; i < 8; ++i) acc[i] = (f32x4){0.f, 0.f, 0.f, 0.f};
#pragma unroll
    for (int ks = 0; ks < KS; ++ks) {
      s16x8 a;
      if constexpr (AF32) {
        const float* ap = (const float*)A0v + (size_t)arow * HID + ks * 32 + kb;
        float4 lo = *(const float4*)ap;
        float4 hi = *(const float4*)(ap + 4);
        i32x4 ai = {(int)pack2(lo.x, lo.y), (int)pack2(lo.z, lo.w),
                    (int)pack2(hi.x, hi.y), (int)pack2(hi.z, hi.w)};
        a = __builtin_bit_cast(s16x8, ai);
      } else if constexpr (DUAL) {
        if (ks < KS / 2) {
          a = *(const s16x8*)((const unsigned short*)A0v + (size_t)arow * HID + ks * 32 + kb);
        } else {
          if constexpr (A1CM)
            a = *(const s16x8*)(A1 + ((size_t)(ks - KS / 2) * N_NODES + arow) * 32 + kb);
          else
            a = *(const s16x8*)(A1 + (size_t)arow * HID + (ks - KS / 2) * 32 + kb);
        }
      } else {
        a = *(const s16x8*)((const unsigned short*)A0v + (size_t)arow * HID + ks * 32 + kb);
      }
#pragma unroll
      for (int nt = 0; nt < 8; ++nt)
        acc[nt] = __builtin_amdgcn_mfma_f32_16x16x32_bf16(a, breg[ks][nt], acc[nt], 0, 0, 0);
    }

    const int rbase = rt * 16 + (lane >> 4) * 4;
    if constexpr (MODE == 2) {
#pragma unroll
      for (int reg = 0; reg < 4; ++reg) {
        int row = rbase + reg;
        float dv = (float)deg[row];
        float v[8];
        float s = 0.f, s2 = 0.f;
#pragma unroll
        for (int nt = 0; nt < 8; ++nt) {
          float hv = bf2f(hres[(size_t)row * HID + nt * 16 + cl]);
          v[nt] = acc[nt][reg] + bs[nt] + dv * b2[nt] + hv;
          s += v[nt];
          s2 += v[nt] * v[nt];
        }
#pragma unroll
        for (int m = 1; m < 16; m <<= 1) {
          s += __shfl_xor(s, m);
          s2 += __shfl_xor(s2, m);
        }
        float mu = s * (1.f / 128.f);
        float var = s2 * (1.f / 128.f) - mu * mu;
        float inv = rsqrtf(var + EPS);
#pragma unroll
        for (int nt = 0; nt < 8; ++nt) {
          float o = (v[nt] - mu) * inv * gs[nt] + bes[nt];
          outB[(size_t)row * HID + nt * 16 + cl] = f2bf(o);
        }
      }
    } else {
#pragma unroll
      for (int reg = 0; reg < 4; ++reg) {
        int row = rbase + reg;
#pragma unroll
        for (int nt = 0; nt < 8; ++nt) {
          float vv = acc[nt][reg] + bs[nt];
          if constexpr (MODE == 0) {
            outF[(size_t)row * outw + co + nt * 16 + cl] = vv;
          } else if constexpr (CMOUT) {
            int grp = by * 4 + (nt >> 1);
            outB[((size_t)grp * N_NODES + row) * 32 + (nt & 1) * 16 + cl] = f2bf(vv);
          } else {
            outB[(size_t)row * outw + co + nt * 16 + cl] = f2bf(vv);
          }
        }
      }
    }
  }
}

// standalone GEMM kernel
template <int KS, bool AF32, bool DUAL, int MODE, bool CMOUT = false, bool A1CM = false>
__global__ __launch_bounds__(256, DUAL ? 1 : 2) void gemm3(
    const void* __restrict__ A0v, const unsigned short* __restrict__ A1,
    const unsigned short* __restrict__ W, const float* __restrict__ bias,
    const int* __restrict__ deg, const float* __restrict__ bias2,
    const float* __restrict__ gamma, const float* __restrict__ beta,
    const unsigned short* __restrict__ hres, float* __restrict__ outF,
    unsigned short* __restrict__ outB, int outw) {
  __shared__ short Bs[KS * 8 * 512];
  gemm3_dev<KS, AF32, DUAL, MODE, CMOUT, A1CM>(Bs, blockIdx.x, gridDim.x, blockIdx.y, A0v,
                                               A1, W, bias, deg, bias2, gamma, beta, hres,
                                               outF, outB, outw);
}

// ================= merged kernels: CSR stages hidden under GEMM =================
union MergedSmem1 { BscatSmem b; short Bs[32 * 512]; };
__global__ __launch_bounds__(256, 2) void k_bscat_enc(
    const int* __restrict__ ei, int* __restrict__ bcursor, unsigned int* __restrict__ ebuf,
    const float* __restrict__ x, const unsigned short* __restrict__ Wenc,
    const float* __restrict__ b_enc, unsigned short* __restrict__ hb) {
  __shared__ MergedSmem1 sm;
  if (blockIdx.x < NSLICE) {
    bscatter_dev(sm.b, ei, bcursor, ebuf, blockIdx.x);
  } else {
    gemm3_dev<4, true, false, 1>(sm.Bs, blockIdx.x - NSLICE, 512, 0, x, nullptr, Wenc, b_enc,
                                 nullptr, nullptr, nullptr, nullptr, nullptr, nullptr, hb, HID);
  }
}

union MergedSmem2 { Sort64Smem s; short Bs[32 * 512]; };
__global__ __launch_bounds__(256, 2) void k_sort_pq(
    const unsigned int* __restrict__ ebuf, const int* __restrict__ boff,
    unsigned short* __restrict__ esrc, int* __restrict__ noff, int* __restrict__ counts,
    const unsigned short* __restrict__ hb, const unsigned short* __restrict__ Wpq,
    unsigned short* __restrict__ pq) {
  __shared__ MergedSmem2 sm;
  if (blockIdx.x < NBKT) {
    sort64_dev(sm.s, ebuf, boff, esrc, noff, counts, blockIdx.x);
  } else {
    int bb = blockIdx.x - NBKT;
    gemm3_dev<4, false, false, 1, true>(sm.Bs, bb & 511, 512, bb >> 9, hb, nullptr, Wpq,
                                        nullptr, nullptr, nullptr, nullptr, nullptr, nullptr,
                                        nullptr, pq, 256);
  }
}

// ================= aggregation: 4-way channel split, uint4 gathers (1 KB/instr) =================
// cg = bid&3 -> 32-channel group; pq/rb group-major [grp][N][32ch] (= [grp][N][4] uint4).
// Wave = 1 node: 16 edge slots x 4 lanes x uint4. Per-XCD hot set = 3.2 MB p-slice (L2-fit).
__global__ __launch_bounds__(256) void aggregate7_kernel(
    const uint4* __restrict__ pqcm,   // [8][N][4]: groups 0-3 = p, 4-7 = q
    const float* __restrict__ bm1,
    const int* __restrict__ noff, const unsigned short* __restrict__ esrc,
    uint4* __restrict__ rbcm) {       // [4][N][4]
  const int cg = blockIdx.x & 3;
  const int chunk = blockIdx.x >> 2;
  const int lane = threadIdx.x & 63;
  const int w = threadIdx.x >> 6;
  const int ch2 = lane & 3;   // uint4 within 32-ch group (8 channels)
  const int es = lane >> 2;   // edge slot 0..15
  const int node = chunk * 4 + w;
  const uint4* pbase = pqcm + (size_t)cg * N_NODES * 4;
  const uint4* qbase = pqcm + (size_t)(4 + cg) * N_NODES * 4;

  uint4 qv = qbase[(size_t)node * 4 + ch2];
  float4 b0 = *(const float4*)(bm1 + cg * 32 + ch2 * 8);
  float4 b1 = *(const float4*)(bm1 + cg * 32 + ch2 * 8 + 4);
  float qf[8] = {bflo(qv.x) + b0.x, bfhi(qv.x) + b0.y, bflo(qv.y) + b0.z, bfhi(qv.y) + b0.w,
                 bflo(qv.z) + b1.x, bfhi(qv.z) + b1.y, bflo(qv.w) + b1.z, bfhi(qv.w) + b1.w};
  float acc[8] = {0.f, 0.f, 0.f, 0.f, 0.f, 0.f, 0.f, 0.f};
  const int i0 = noff[node], i1 = noff[node + 1];
  const int nfull = (i1 - i0) >> 4;  // 16 edges per full wave-iter
  int idx = i0 + es;
  for (int j = 0; j < nfull; ++j, idx += 16) {
    int src = esrc[idx];
    uint4 u = pbase[(size_t)src * 4 + ch2];
    acc[0] += fmaxf(bflo(u.x) + qf[0], 0.f);
    acc[1] += fmaxf(bfhi(u.x) + qf[1], 0.f);
    acc[2] += fmaxf(bflo(u.y) + qf[2], 0.f);
    acc[3] += fmaxf(bfhi(u.y) + qf[3], 0.f);
    acc[4] += fmaxf(bflo(u.z) + qf[4], 0.f);
    acc[5] += fmaxf(bfhi(u.z) + qf[5], 0.f);
    acc[6] += fmaxf(bflo(u.w) + qf[6], 0.f);
    acc[7] += fmaxf(bfhi(u.w) + qf[7], 0.f);
  }
  if (idx < i1) {  // tail <16 edges, exec-masked
    int src = esrc[idx];
    uint4 u = pbase[(size_t)src * 4 + ch2];
    acc[0] += fmaxf(bflo(u.x) + qf[0], 0.f);
    acc[1] += fmaxf(bfhi(u.x) + qf[1], 0.f);
    acc[2] += fmaxf(bflo(u.y) + qf[2], 0.f);
    acc[3] += fmaxf(bfhi(u.y) + qf[3], 0.f);
    acc[4] += fmaxf(bflo(u.z) + qf[4], 0.f);
    acc[5] += fmaxf(bfhi(u.z) + qf[5], 0.f);
    acc[6] += fmaxf(bflo(u.w) + qf[6], 0.f);
    acc[7] += fmaxf(bfhi(u.w) + qf[7], 0.f);
  }
#pragma unroll
  for (int j = 0; j < 8; ++j) {
    acc[j] += __shfl_xor(acc[j], 4);
    acc[j] += __shfl_xor(acc[j], 8);
    acc[j] += __shfl_xor(acc[j], 16);
    acc[j] += __shfl_xor(acc[j], 32);
  }
  if (es == 0) {
    uint4 r;
    r.x = pack2(acc[0], acc[1]);
    r.y = pack2(acc[2], acc[3]);
    r.z = pack2(acc[4], acc[5]);
    r.w = pack2(acc[6], acc[7]);
    rbcm[((size_t)cg * N_NODES + node) * 4 + ch2] = r;
  }
}

extern "C" void kernel_launch(void* const* d_in, const int* in_sizes, int n_in,
                              void* d_out, int out_size, void* d_ws, size_t ws_size,
                              hipStream_t stream) {
  const float* x     = (const float*)d_in[0];
  const int*   ei    = (const int*)d_in[1];
  const float* W_enc = (const float*)d_in[2];
  const float* b_enc = (const float*)d_in[3];
  const float* Wm1   = (const float*)d_in[4];
  const float* bm1   = (const float*)d_in[5];
  const float* Wm2   = (const float*)d_in[6];
  const float* bm2   = (const float*)d_in[7];
  const float* Wu    = (const float*)d_in[8];
  const float* bu    = (const float*)d_in[9];
  const float* gamma = (const float*)d_in[10];
  const float* beta  = (const float*)d_in[11];
  const float* W_out = (const float*)d_in[12];
  const float* b_out = (const float*)d_in[13];
  float* out = (float*)d_out;

  char* ws = (char*)d_ws;
  const size_t NBH = (size_t)N_NODES * HID * 2;  // 12.8 MB

  unsigned short* hb = (unsigned short*)(ws);            // [N][128] bf16 row-major
  unsigned short* pq = (unsigned short*)(ws + NBH);      // [8][N][32] bf16 group-major
  unsigned short* rb = (unsigned short*)(ws + 3 * NBH);  // [4][N][32] bf16 group-major
  char* wp = ws + 4 * NBH;
  unsigned short* Wenc_b = (unsigned short*)wp;          // 16384
  unsigned short* Wout_b = Wenc_b + 16384;               // 16384
  unsigned short* Wpq_b  = Wout_b + 16384;               // 2*32768
  unsigned short* Wcat_b = Wpq_b + 65536;                // 2*32768
  float*          bfold  = (float*)(Wcat_b + 65536);     // 256
  int* counts  = (int*)(bfold + 256);                    // [N] deg
  int* noff    = counts + N_NODES;                       // [N+1] exact CSR offsets
  int* boff    = noff + N_NODES + 1;                     // NBKT+1
  int* bcursor = boff + NBKT + 1;                        // NBKT
  unsigned short* esrc = (unsigned short*)(bcursor + NBKT);  // [E] u16 src by exact dst
  unsigned int* ebuf = (unsigned int*)(esrc + N_EDGES);      // [E] bucket-grouped
  int* shist = (int*)(ebuf + N_EDGES);                       // [NSLICE][NBKT]

  // 1. weight prep || per-slice bucket histograms
  prep_hist_kernel<<<449 + NSLICE, 256, 0, stream>>>(
      W_enc, W_out, Wm1, Wu, Wm2, bm2, (unsigned int*)Wenc_b, (unsigned int*)Wout_b,
      (unsigned int*)Wpq_b, Wcat_b, bfold, ei, shist);
  // 2. fused column-sum + exclusive scan
  bscan_kernel<<<1, 1024, 0, stream>>>(shist, boff, bcursor);
  // 3. bucket scatter || enc GEMM (h = x @ W_enc.T + b_enc -> bf16 hb)
  k_bscat_enc<<<NSLICE + 512, 256, 0, stream>>>(ei, bcursor, ebuf, x, Wenc_b, b_enc, hb);
  // 4. sort64 (exact CSR) || pq GEMM layer 0 (group-major out)
  k_sort_pq<<<NBKT + 1024, 256, 0, stream>>>(ebuf, boff, esrc, noff, counts, hb, Wpq_b, pq);

  for (int l = 0; l < 2; ++l) {
    const unsigned short* Wcatl = Wcat_b + l * 32768;
    const float* bm1l = bm1 + l * HID;
    const float* bul  = bu + l * HID;
    const float* bfl  = bfold + l * HID;
    const float* gl   = gamma + l * HID;
    const float* bl   = beta + l * HID;

    // r = segsum(relu(p[src]+q[dst]+bm1)), 4-way channel split (cg = bid&3)
    aggregate7_kernel<<<12500 * 4, 256, 0, stream>>>((const uint4*)pq, bm1l, noff, esrc,
                                                     (uint4*)rb);
    // h = LN(h + h@Wua.T + r@Wfold.T + deg*bfold + bu)*gamma+beta (in-place; rb group-major)
    gemm3<8, false, true, 2, false, true><<<256, 256, 0, stream>>>(
        hb, rb, Wcatl, bul, counts, bfl, gl, bl, hb, nullptr, hb, HID);
    // pq for layer 1 (group-major out)
    if (l == 0)
      gemm3<4, false, false, 1, true><<<dim3(512, 2), 256, 0, stream>>>(
          hb, nullptr, Wpq_b + 32768, nullptr, nullptr, nullptr, nullptr, nullptr, nullptr,
          nullptr, pq, 256);
  }

  // out = h @ W_out.T + b_out (f32)
  gemm3<4, false, false, 0><<<512, 256, 0, stream>>>(
      hb, nullptr, Wout_b, b_out, nullptr, nullptr, nullptr, nullptr, nullptr,
      out, nullptr, HID);
}

// Round 14
// 203.201 us; speedup vs baseline: 1.4644x; 1.3820x over previous
//
#include <hip/hip_runtime.h>

#define N_NODES 50000
#define N_EDGES 800000
#define HID 128
#define EPS 1e-5f
#define NBKT 782            // ceil(50000/64) buckets of 64 dst nodes
#define ESLICE 3125         // edges per scatter/hist block (256 blocks)
#define NSLICE 256

typedef __attribute__((ext_vector_type(8))) short s16x8;   // 8 bf16 (4 VGPRs)
typedef __attribute__((ext_vector_type(4))) float f32x4;   // MFMA acc
typedef __attribute__((ext_vector_type(4))) int i32x4;

__device__ __forceinline__ unsigned short f2bf(float f) {  // RNE f32->bf16
  unsigned int u = __float_as_uint(f);
  u += 0x7fffu + ((u >> 16) & 1u);
  return (unsigned short)(u >> 16);
}
__device__ __forceinline__ unsigned int pack2(float a, float b) {
  return (unsigned int)f2bf(a) | ((unsigned int)f2bf(b) << 16);
}
__device__ __forceinline__ float bflo(unsigned int u) { return __uint_as_float(u << 16); }
__device__ __forceinline__ float bfhi(unsigned int u) { return __uint_as_float(u & 0xffff0000u); }
__device__ __forceinline__ float bf2f(unsigned short u) { return __uint_as_float((unsigned int)u << 16); }

// ================= weight prep (blocks 0..448)  ||  bucket hist (blocks 449..704) =================
__global__ __launch_bounds__(256) void prep_hist_kernel(
    const float* __restrict__ W_enc, const float* __restrict__ W_out,
    const float* __restrict__ Wm1, const float* __restrict__ Wu,
    const float* __restrict__ Wm2, const float* __restrict__ bm2,
    unsigned int* __restrict__ Wenc_b, unsigned int* __restrict__ Wout_b,
    unsigned int* __restrict__ Wpq_b, unsigned short* __restrict__ Wcat_b,
    float* __restrict__ bfold, const int* __restrict__ ei, int* __restrict__ shist) {
  __shared__ int lhist[NBKT];
  const int b = blockIdx.x, t = threadIdx.x;
  if (b >= 449) {  // ---- bucket histogram (one slice per block) ----
    const int sl = b - 449;
    const int e0 = sl * ESLICE;
    for (int i = t; i < NBKT; i += 256) lhist[i] = 0;
    __syncthreads();
    for (int e = e0 + t; e < e0 + ESLICE; e += 256)
      atomicAdd(&lhist[ei[N_EDGES + e] >> 6], 1);
    __syncthreads();
    for (int i = t; i < NBKT; i += 256) shist[sl * NBKT + i] = lhist[i];
    return;
  }
  if (b < 32) {            // W_enc: 8192 uints
    int i = b * 256 + t;
    Wenc_b[i] = pack2(W_enc[2 * i], W_enc[2 * i + 1]);
  } else if (b < 64) {     // W_out
    int i = (b - 32) * 256 + t;
    Wout_b[i] = pack2(W_out[2 * i], W_out[2 * i + 1]);
  } else if (b < 192) {    // repack Wm1 -> Wpq [l][256 rows][128 k]
    int i = (b - 64) * 256 + t;  // 32768
    int k2 = i & 63;
    int c = (i >> 6) & 255;
    int l = i >> 14;
    const float* srow = Wm1 + ((size_t)l * 128 + (c & 127)) * 256 + ((c >> 7) << 7);
    Wpq_b[i] = pack2(srow[2 * k2], srow[2 * k2 + 1]);
  } else if (b < 448) {    // Wcat: [l][128 rows][256 k], hi-k = Wu_b @ Wm2 fold
    int i = (b - 192) * 256 + t;  // 65536
    int k = i & 255, c = (i >> 8) & 127, l = i >> 15;
    const float* wrow = Wu + ((size_t)l * 128 + c) * 256;
    float v;
    if (k < 128) {
      v = wrow[k];
    } else {
      const float* wb = wrow + 128;
      const float* m2 = Wm2 + (size_t)l * 128 * 128 + (k - 128);
      float s = 0.f;
      for (int j = 0; j < 128; ++j) s += wb[j] * m2[(size_t)j * 128];
      v = s;
    }
    Wcat_b[i] = f2bf(v);
  } else {                 // bfold[l][c] = Wu_b[l][c][:] . bm2[l]
    int l = t >> 7, c = t & 127;
    const float* wb = Wu + ((size_t)l * 128 + c) * 256 + 128;
    const float* bv = bm2 + l * 128;
    float s = 0.f;
    for (int j = 0; j < 128; ++j) s += wb[j] * bv[j];
    bfold[t] = s;
  }
}

// ================= bucket scan (with fused column-sum of slice hists) =================
__global__ __launch_bounds__(1024) void bscan_kernel(const int* __restrict__ shist,
                                                     int* __restrict__ boff,
                                                     int* __restrict__ bcursor) {
  __shared__ int wtot[16];
  const int t = threadIdx.x, lane = t & 63, w = t >> 6;
  int v = 0;
  if (t < NBKT)
    for (int j = 0; j < NSLICE; ++j) v += shist[j * NBKT + t];  // coalesced across t
  int s = v;
#pragma unroll
  for (int off = 1; off < 64; off <<= 1) {
    int tt = __shfl_up(s, off);
    if (lane >= off) s += tt;
  }
  if (lane == 63) wtot[w] = s;
  __syncthreads();
  int woff = 0;
#pragma unroll
  for (int j = 0; j < 16; ++j) { int tv = wtot[j]; if (j < w) woff += tv; }
  int excl = woff + (s - v);
  if (t < NBKT) { boff[t] = excl; bcursor[t] = excl; }
  if (t == NBKT) boff[NBKT] = excl;  // v=0 here -> excl == total
}

// ================= device-fn bodies for merged kernels =================
struct BscatSmem {
  int lhist[784], lstart[784], lcur[784], gbase[784];
  unsigned int staged[ESLICE];
  int wtot[4];
};
struct Sort64Smem { int hist[64]; int lcur[64]; };

// bucket scatter: 2-pass LDS counting sort per 3125-edge slice.
__device__ __forceinline__ void bscatter_dev(BscatSmem& sm, const int* ei, int* bcursor,
                                             unsigned int* ebuf, int bx) {
  const int t = threadIdx.x, lane = t & 63, w = t >> 6;
  const int e0 = bx * ESLICE;

  for (int i = t; i < 784; i += 256) sm.lhist[i] = 0;
  __syncthreads();
  for (int e = e0 + t; e < e0 + ESLICE; e += 256)
    atomicAdd(&sm.lhist[ei[N_EDGES + e] >> 6], 1);
  __syncthreads();

  int tsum = 0;
  if (t < 196)
    tsum = sm.lhist[4 * t] + sm.lhist[4 * t + 1] + sm.lhist[4 * t + 2] + sm.lhist[4 * t + 3];
  int inc = tsum;
#pragma unroll
  for (int off = 1; off < 64; off <<= 1) {
    int tt = __shfl_up(inc, off);
    if (lane >= off) inc += tt;
  }
  if (lane == 63) sm.wtot[w] = inc;
  __syncthreads();
  int woff = 0;
#pragma unroll
  for (int j = 0; j < 4; ++j) { int tv = sm.wtot[j]; if (j < w) woff += tv; }
  if (t < 196) {
    int run = woff + inc - tsum;
#pragma unroll
    for (int j = 0; j < 4; ++j) {
      sm.lstart[4 * t + j] = run;
      sm.lcur[4 * t + j] = run;
      run += sm.lhist[4 * t + j];
    }
  }
  for (int bk = t; bk < NBKT; bk += 256)
    sm.gbase[bk] = sm.lhist[bk] ? atomicAdd(&bcursor[bk], sm.lhist[bk]) : 0;
  __syncthreads();

  for (int e = e0 + t; e < e0 + ESLICE; e += 256) {
    int s = ei[e], d = ei[N_EDGES + e];
    int pos = atomicAdd(&sm.lcur[d >> 6], 1);
    sm.staged[pos] = (unsigned int)s | ((unsigned int)(d & 63) << 16) |
                     ((unsigned int)(d >> 6) << 22);
  }
  __syncthreads();

  for (int i = t; i < ESLICE; i += 256) {
    unsigned int pk = sm.staged[i];
    int bk = pk >> 22;
    ebuf[sm.gbase[bk] + (i - sm.lstart[bk])] = pk;
  }
}

// sort64: bucket -> exact per-node CSR; esrc stored as u16 (src < 65536).
__device__ __forceinline__ void sort64_dev(Sort64Smem& sm, const unsigned int* ebuf,
                                           const int* boff, unsigned short* esrc,
                                           int* noff, int* counts, int b) {
  const int t = threadIdx.x;
  const int e0 = boff[b], e1 = boff[b + 1];
  if (t < 64) sm.hist[t] = 0;
  __syncthreads();
  for (int e = e0 + t; e < e1; e += 256)
    atomicAdd(&sm.hist[(ebuf[e] >> 16) & 63], 1);
  __syncthreads();
  if (t < 64) {
    int v = sm.hist[t];
    int s = v;
#pragma unroll
    for (int off = 1; off < 64; off <<= 1) {
      int tt = __shfl_up(s, off);
      if (t >= off) s += tt;
    }
    sm.lcur[t] = s - v;
    int node = b * 64 + t;
    if (node < N_NODES) {
      noff[node] = e0 + s - v;
      counts[node] = v;
    }
  }
  __syncthreads();
  for (int e = e0 + t; e < e1; e += 256) {
    unsigned int pk = ebuf[e];
    int pos = atomicAdd(&sm.lcur[(pk >> 16) & 63], 1);
    esrc[e0 + pos] = (unsigned short)(pk & 0xffffu);
  }
  if (b == NBKT - 1 && t == 0) noff[N_NODES] = e1;
}

// ================= persistent-B MFMA GEMM body (row-major layouts everywhere) =========
template <int KS, bool AF32, bool DUAL, int MODE>
__device__ __forceinline__ void gemm3_dev(
    short* Bs, int bx, int gx, int by,
    const void* A0v, const unsigned short* A1,
    const unsigned short* W, const float* bias,
    const int* deg, const float* bias2,
    const float* gamma, const float* beta,
    const unsigned short* hres, float* outF,
    unsigned short* outB, int outw) {
  constexpr int KW = KS * 32;
  constexpr int NFRAG = KS * 8;
  const int lane = threadIdx.x & 63;
  const int w = threadIdx.x >> 6;
  const int cl = lane & 15;
  const int kb = (lane >> 4) * 8;
  const int co = by * 128;
  W += (size_t)by * 128 * KW;

  for (int f = w; f < NFRAG; f += 4) {
    int nt = f & 7, ks = f >> 3;
    s16x8 bv = *(const s16x8*)(W + (size_t)(nt * 16 + cl) * KW + ks * 32 + kb);
    *(s16x8*)(Bs + f * 512 + lane * 8) = bv;
  }
  __syncthreads();

  s16x8 breg[KS][8];
#pragma unroll
  for (int ks = 0; ks < KS; ++ks)
#pragma unroll
    for (int nt = 0; nt < 8; ++nt)
      breg[ks][nt] = *(const s16x8*)(Bs + (ks * 8 + nt) * 512 + lane * 8);

  float bs[8], b2[8], gs[8], bes[8];
#pragma unroll
  for (int nt = 0; nt < 8; ++nt) {
    int col = nt * 16 + cl;
    bs[nt] = bias ? bias[col] : 0.f;
    if constexpr (MODE == 2) {
      b2[nt] = bias2[col];
      gs[nt] = gamma[col];
      bes[nt] = beta[col];
    }
  }

  const int step = gx * 4;
  for (int rt = bx * 4 + w; rt < 3125; rt += step) {  // 3125*16 == 50000
    const int arow = rt * 16 + cl;
    f32x4 acc[8];
#pragma unroll
    for (int i = 0; i < 8; ++i) acc[i] = (f32x4){0.f, 0.f, 0.f, 0.f};
#pragma unroll
    for (int ks = 0; ks < KS; ++ks) {
      s16x8 a;
      if constexpr (AF32) {
        const float* ap = (const float*)A0v + (size_t)arow * HID + ks * 32 + kb;
        float4 lo = *(const float4*)ap;
        float4 hi = *(const float4*)(ap + 4);
        i32x4 ai = {(int)pack2(lo.x, lo.y), (int)pack2(lo.z, lo.w),
                    (int)pack2(hi.x, hi.y), (int)pack2(hi.z, hi.w)};
        a = __builtin_bit_cast(s16x8, ai);
      } else if constexpr (DUAL) {
        const unsigned short* base = (ks < KS / 2) ? (const unsigned short*)A0v : A1;
        int kss = (ks < KS / 2) ? ks : ks - KS / 2;
        a = *(const s16x8*)(base + (size_t)arow * HID + kss * 32 + kb);
      } else {
        a = *(const s16x8*)((const unsigned short*)A0v + (size_t)arow * HID + ks * 32 + kb);
      }
#pragma unroll
      for (int nt = 0; nt < 8; ++nt)
        acc[nt] = __builtin_amdgcn_mfma_f32_16x16x32_bf16(a, breg[ks][nt], acc[nt], 0, 0, 0);
    }

    const int rbase = rt * 16 + (lane >> 4) * 4;
    if constexpr (MODE == 2) {
#pragma unroll
      for (int reg = 0; reg < 4; ++reg) {
        int row = rbase + reg;
        float dv = (float)deg[row];
        float v[8];
        float s = 0.f, s2 = 0.f;
#pragma unroll
        for (int nt = 0; nt < 8; ++nt) {
          float hv = bf2f(hres[(size_t)row * HID + nt * 16 + cl]);
          v[nt] = acc[nt][reg] + bs[nt] + dv * b2[nt] + hv;
          s += v[nt];
          s2 += v[nt] * v[nt];
        }
#pragma unroll
        for (int m = 1; m < 16; m <<= 1) {
          s += __shfl_xor(s, m);
          s2 += __shfl_xor(s2, m);
        }
        float mu = s * (1.f / 128.f);
        float var = s2 * (1.f / 128.f) - mu * mu;
        float inv = rsqrtf(var + EPS);
#pragma unroll
        for (int nt = 0; nt < 8; ++nt) {
          float o = (v[nt] - mu) * inv * gs[nt] + bes[nt];
          outB[(size_t)row * HID + nt * 16 + cl] = f2bf(o);
        }
      }
    } else {
#pragma unroll
      for (int reg = 0; reg < 4; ++reg) {
        int row = rbase + reg;
#pragma unroll
        for (int nt = 0; nt < 8; ++nt) {
          float vv = acc[nt][reg] + bs[nt];
          if constexpr (MODE == 0) outF[(size_t)row * outw + co + nt * 16 + cl] = vv;
          else outB[(size_t)row * outw + co + nt * 16 + cl] = f2bf(vv);
        }
      }
    }
  }
}

// standalone GEMM kernel
template <int KS, bool AF32, bool DUAL, int MODE>
__global__ __launch_bounds__(256, DUAL ? 1 : 2) void gemm3(
    const void* __restrict__ A0v, const unsigned short* __restrict__ A1,
    const unsigned short* __restrict__ W, const float* __restrict__ bias,
    const int* __restrict__ deg, const float* __restrict__ bias2,
    const float* __restrict__ gamma, const float* __restrict__ beta,
    const unsigned short* __restrict__ hres, float* __restrict__ outF,
    unsigned short* __restrict__ outB, int outw) {
  __shared__ short Bs[KS * 8 * 512];
  gemm3_dev<KS, AF32, DUAL, MODE>(Bs, blockIdx.x, gridDim.x, blockIdx.y, A0v, A1, W, bias,
                                  deg, bias2, gamma, beta, hres, outF, outB, outw);
}

// ================= merged kernels: CSR stages hidden under GEMM =================
union MergedSmem1 { BscatSmem b; short Bs[32 * 512]; };
__global__ __launch_bounds__(256, 2) void k_bscat_enc(
    const int* __restrict__ ei, int* __restrict__ bcursor, unsigned int* __restrict__ ebuf,
    const float* __restrict__ x, const unsigned short* __restrict__ Wenc,
    const float* __restrict__ b_enc, unsigned short* __restrict__ hb) {
  __shared__ MergedSmem1 sm;
  if (blockIdx.x < NSLICE) {
    bscatter_dev(sm.b, ei, bcursor, ebuf, blockIdx.x);
  } else {
    gemm3_dev<4, true, false, 1>(sm.Bs, blockIdx.x - NSLICE, 512, 0, x, nullptr, Wenc, b_enc,
                                 nullptr, nullptr, nullptr, nullptr, nullptr, nullptr, hb, HID);
  }
}

union MergedSmem2 { Sort64Smem s; short Bs[32 * 512]; };
__global__ __launch_bounds__(256, 2) void k_sort_pq(
    const unsigned int* __restrict__ ebuf, const int* __restrict__ boff,
    unsigned short* __restrict__ esrc, int* __restrict__ noff, int* __restrict__ counts,
    const unsigned short* __restrict__ hb, const unsigned short* __restrict__ Wpq,
    unsigned short* __restrict__ pq) {
  __shared__ MergedSmem2 sm;
  if (blockIdx.x < NBKT) {
    sort64_dev(sm.s, ebuf, boff, esrc, noff, counts, blockIdx.x);
  } else {
    int bb = blockIdx.x - NBKT;
    gemm3_dev<4, false, false, 1>(sm.Bs, bb & 511, 512, bb >> 9, hb, nullptr, Wpq, nullptr,
                                  nullptr, nullptr, nullptr, nullptr, nullptr, nullptr, pq, 256);
  }
}

// ================= aggregation: wave per node, uint4 gathers (16 lanes/row), 16 edges/iter ==
__device__ __forceinline__ void acc8(float* acc, const float* qf, uint4 u) {
  acc[0] += fmaxf(bflo(u.x) + qf[0], 0.f);
  acc[1] += fmaxf(bfhi(u.x) + qf[1], 0.f);
  acc[2] += fmaxf(bflo(u.y) + qf[2], 0.f);
  acc[3] += fmaxf(bfhi(u.y) + qf[3], 0.f);
  acc[4] += fmaxf(bflo(u.z) + qf[4], 0.f);
  acc[5] += fmaxf(bfhi(u.z) + qf[5], 0.f);
  acc[6] += fmaxf(bflo(u.w) + qf[6], 0.f);
  acc[7] += fmaxf(bfhi(u.w) + qf[7], 0.f);
}

__global__ __launch_bounds__(256) void aggregate5_kernel(
    const uint4* __restrict__ pq4, const float* __restrict__ bm1,
    const int* __restrict__ noff, const unsigned short* __restrict__ esrc,
    uint4* __restrict__ rb4) {
  const int node = blockIdx.x * 4 + (threadIdx.x >> 6);
  const int lane = threadIdx.x & 63;
  const int l = lane & 15;   // uint4 slot: channels 8l..8l+7
  const int eh = lane >> 4;  // edge slot within group of 4
  uint4 qv = pq4[(size_t)node * 32 + 16 + l];  // q-half
  float4 b0 = *(const float4*)(bm1 + 8 * l);
  float4 b1 = *(const float4*)(bm1 + 8 * l + 4);
  float qf[8] = {bflo(qv.x) + b0.x, bfhi(qv.x) + b0.y, bflo(qv.y) + b0.z, bfhi(qv.y) + b0.w,
                 bflo(qv.z) + b1.x, bfhi(qv.z) + b1.y, bflo(qv.w) + b1.z, bfhi(qv.w) + b1.w};
  float acc[8] = {0.f, 0.f, 0.f, 0.f, 0.f, 0.f, 0.f, 0.f};
  const int i0 = noff[node], i1 = noff[node + 1];
  const int nfull = (i1 - i0) >> 4;  // 16 edges per full wave-iter
  int idx = i0 + eh;
  for (int j = 0; j < nfull; ++j, idx += 16) {
    int s0 = esrc[idx], s1 = esrc[idx + 4], s2 = esrc[idx + 8], s3 = esrc[idx + 12];
    uint4 u0 = pq4[(size_t)s0 * 32 + l];
    uint4 u1 = pq4[(size_t)s1 * 32 + l];
    uint4 u2 = pq4[(size_t)s2 * 32 + l];
    uint4 u3 = pq4[(size_t)s3 * 32 + l];
    acc8(acc, qf, u0);
    acc8(acc, qf, u1);
    acc8(acc, qf, u2);
    acc8(acc, qf, u3);
  }
  while (idx < i1) {  // tail: <16 edges, 4 at a time, exec-masked
    uint4 u = pq4[(size_t)esrc[idx] * 32 + l];
    acc8(acc, qf, u);
    idx += 4;
  }
#pragma unroll
  for (int j = 0; j < 8; ++j) {
    acc[j] += __shfl_xor(acc[j], 16);
    acc[j] += __shfl_xor(acc[j], 32);
  }
  if (lane < 16) {
    uint4 r;
    r.x = pack2(acc[0], acc[1]);
    r.y = pack2(acc[2], acc[3]);
    r.z = pack2(acc[4], acc[5]);
    r.w = pack2(acc[6], acc[7]);
    rb4[(size_t)node * 16 + l] = r;
  }
}

extern "C" void kernel_launch(void* const* d_in, const int* in_sizes, int n_in,
                              void* d_out, int out_size, void* d_ws, size_t ws_size,
                              hipStream_t stream) {
  const float* x     = (const float*)d_in[0];
  const int*   ei    = (const int*)d_in[1];
  const float* W_enc = (const float*)d_in[2];
  const float* b_enc = (const float*)d_in[3];
  const float* Wm1   = (const float*)d_in[4];
  const float* bm1   = (const float*)d_in[5];
  const float* Wm2   = (const float*)d_in[6];
  const float* bm2   = (const float*)d_in[7];
  const float* Wu    = (const float*)d_in[8];
  const float* bu    = (const float*)d_in[9];
  const float* gamma = (const float*)d_in[10];
  const float* beta  = (const float*)d_in[11];
  const float* W_out = (const float*)d_in[12];
  const float* b_out = (const float*)d_in[13];
  float* out = (float*)d_out;

  char* ws = (char*)d_ws;
  const size_t NBH = (size_t)N_NODES * HID * 2;  // 12.8 MB

  unsigned short* hb = (unsigned short*)(ws);            // [N][128] bf16
  unsigned short* pq = (unsigned short*)(ws + NBH);      // [N][256] bf16 row-major
  unsigned short* rb = (unsigned short*)(ws + 3 * NBH);  // [N][128] bf16 row-major
  char* wp = ws + 4 * NBH;
  unsigned short* Wenc_b = (unsigned short*)wp;          // 16384
  unsigned short* Wout_b = Wenc_b + 16384;               // 16384
  unsigned short* Wpq_b  = Wout_b + 16384;               // 2*32768
  unsigned short* Wcat_b = Wpq_b + 65536;                // 2*32768
  float*          bfold  = (float*)(Wcat_b + 65536);     // 256
  int* counts  = (int*)(bfold + 256);                    // [N] deg
  int* noff    = counts + N_NODES;                       // [N+1] exact CSR offsets
  int* boff    = noff + N_NODES + 1;                     // NBKT+1
  int* bcursor = boff + NBKT + 1;                        // NBKT
  unsigned short* esrc = (unsigned short*)(bcursor + NBKT);  // [E] u16 src by exact dst
  unsigned int* ebuf = (unsigned int*)(esrc + N_EDGES);      // [E] bucket-grouped
  int* shist = (int*)(ebuf + N_EDGES);                       // [NSLICE][NBKT]

  // 1. weight prep || per-slice bucket histograms
  prep_hist_kernel<<<449 + NSLICE, 256, 0, stream>>>(
      W_enc, W_out, Wm1, Wu, Wm2, bm2, (unsigned int*)Wenc_b, (unsigned int*)Wout_b,
      (unsigned int*)Wpq_b, Wcat_b, bfold, ei, shist);
  // 2. fused column-sum + exclusive scan
  bscan_kernel<<<1, 1024, 0, stream>>>(shist, boff, bcursor);
  // 3. bucket scatter || enc GEMM (h = x @ W_enc.T + b_enc -> bf16 hb)
  k_bscat_enc<<<NSLICE + 512, 256, 0, stream>>>(ei, bcursor, ebuf, x, Wenc_b, b_enc, hb);
  // 4. sort64 (exact CSR) || pq GEMM layer 0 (row-major [N][256] out)
  k_sort_pq<<<NBKT + 1024, 256, 0, stream>>>(ebuf, boff, esrc, noff, counts, hb, Wpq_b, pq);

  for (int l = 0; l < 2; ++l) {
    const unsigned short* Wcatl = Wcat_b + l * 32768;
    const float* bm1l = bm1 + l * HID;
    const float* bul  = bu + l * HID;
    const float* bfl  = bfold + l * HID;
    const float* gl   = gamma + l * HID;
    const float* bl   = beta + l * HID;

    // r = segsum(relu(p[src]+q[dst]+bm1)) over exact per-node runs
    aggregate5_kernel<<<12500, 256, 0, stream>>>((const uint4*)pq, bm1l, noff, esrc,
                                                 (uint4*)rb);
    // h = LN(h + h@Wua.T + r@Wfold.T + deg*bfold + bu)*gamma+beta (in-place; rb row-major)
    gemm3<8, false, true, 2><<<256, 256, 0, stream>>>(
        hb, rb, Wcatl, bul, counts, bfl, gl, bl, hb, nullptr, hb, HID);
    // pq for layer 1 (row-major out)
    if (l == 0)
      gemm3<4, false, false, 1><<<dim3(512, 2), 256, 0, stream>>>(
          hb, nullptr, Wpq_b + 32768, nullptr, nullptr, nullptr, nullptr, nullptr, nullptr,
          nullptr, pq, 256);
  }

  // out = h @ W_out.T + b_out (f32)
  gemm3<4, false, false, 0><<<512, 256, 0, stream>>>(
      hb, nullptr, Wout_b, b_out, nullptr, nullptr, nullptr, nullptr, nullptr,
      out, nullptr, HID);
}